// Round 1
// baseline (934.791 us; speedup 1.0000x reference)
//
#include <hip/hip_runtime.h>
#include <hip/hip_bf16.h>
#include <stdint.h>

typedef short s4v    __attribute__((ext_vector_type(4)));
typedef short short8 __attribute__((ext_vector_type(8)));
typedef float f32x4  __attribute__((ext_vector_type(4)));
typedef float floatx4 __attribute__((ext_vector_type(4)));

#define MFMA16(a,b,c) __builtin_amdgcn_mfma_f32_16x16x32_bf16((a),(b),(c),0,0,0)

typedef __attribute__((address_space(3))) void* lds_ptr_t;
typedef __attribute__((address_space(1))) void* gbl_ptr_t;

// async global->LDS, 16B/lane; LDS dest = wave-uniform base + lane*16.
__device__ __forceinline__ void gll16(const void* g, void* l) {
  __builtin_amdgcn_global_load_lds((gbl_ptr_t)g, (lds_ptr_t)l, 16, 0, 0);
}

__device__ __forceinline__ short f2b(float f) {
  return __builtin_bit_cast(short, __float2bfloat16(f));
}
__device__ __forceinline__ float b2f(short s) {
  return __bfloat162float(__builtin_bit_cast(__hip_bfloat16, s));
}
__device__ __forceinline__ float loadf(const void* p, size_t i, int isbf) {
  return isbf ? b2f(((const short*)p)[i]) : ((const float*)p)[i];
}

// ---------------------------------------------------------------------------
// Dtype sniffer (1 = bf16, 0 = fp32), written to device flag.
// ---------------------------------------------------------------------------
__global__ void sniff_dtype(const uint32_t* __restrict__ X, int* __restrict__ flag)
{
  const int t = threadIdx.x;
  const uint32_t w = X[t];
  const uint32_t b = (w >> 8) & 0x7fu;
  const int hit = (b >= 0x38u && b <= 0x41u) ? 1 : 0;
  const unsigned long long m = __ballot(hit);
  if (t == 0) flag[0] = (__popcll(m) > 32) ? 1 : 0;
}

// ---------------------------------------------------------------------------
// Transpose 5 512x512 weights into bf16 Wt[n][k].
// ---------------------------------------------------------------------------
__global__ __launch_bounds__(256)
void transpose_w(const void* __restrict__ Wq, const void* __restrict__ Wk,
                 const void* __restrict__ Wv, const void* __restrict__ W1,
                 const void* __restrict__ W2, short* __restrict__ Out,
                 const int* __restrict__ dflag)
{
  __shared__ short tile[64][65];
  const int isbf = *dflag;
  const int b = blockIdx.x;          // 5 * 64
  const int w = b >> 6;
  const int t = b & 63;
  const int ty = t >> 3, tx = t & 7;
  const void* W = (w==0)?Wq:(w==1)?Wk:(w==2)?Wv:(w==3)?W1:W2;
  short* Og = Out + (size_t)w * 262144;
  const int tid = threadIdx.x;
#pragma unroll
  for (int i=0;i<16;++i) {
    const int idx = tid + i*256;
    const int rr = idx>>6, cc = idx&63;
    tile[rr][cc] = f2b(loadf(W, (size_t)(ty*64+rr)*512 + tx*64 + cc, isbf));
  }
  __syncthreads();
#pragma unroll
  for (int i=0;i<16;++i) {
    const int idx = tid + i*256;
    const int co = idx>>6, ko = idx&63;
    Og[(size_t)(tx*64+co)*512 + ty*64 + ko] = tile[ko][co];
  }
}

// ---------------------------------------------------------------------------
// One-shot X convert: fp32 (or bf16 passthrough) -> bf16 row-major, so the
// QKV GEMMs can use the global_load_lds width-16 staging path.
// ---------------------------------------------------------------------------
__global__ __launch_bounds__(256)
void cvt_x(const void* __restrict__ X, short* __restrict__ Xb,
           const int* __restrict__ dflag)
{
  const int isbf = *dflag;
  const size_t n8 = (size_t)49152 * 512 / 8;
  const size_t stride = (size_t)gridDim.x * 256;
  for (size_t i = (size_t)blockIdx.x * 256 + threadIdx.x; i < n8; i += stride) {
    if (isbf) {
      *(short8*)&Xb[i*8] = *(const short8*)&((const short*)X)[i*8];
    } else {
      const f32x4 f0 = *(const f32x4*)&((const float*)X)[i*8];
      const f32x4 f1 = *(const f32x4*)&((const float*)X)[i*8+4];
      short8 o;
#pragma unroll
      for (int j=0;j<4;++j) { o[j] = f2b(f0[j]); o[4+j] = f2b(f1[j]); }
      *(short8*)&Xb[i*8] = o;
    }
  }
}

// ---------------------------------------------------------------------------
// GEMM: C[M,512] = act(A[M,512] @ Bt^T + bias), M=49152. 128x128 tile, BK=32,
// 4 waves, m97 structure. MFMA operands SWAPPED (mfma(B,A)) so each lane's
// 4 accumulator values are 4 CONSECUTIVE output columns -> packed 8B/16B
// epilogue stores instead of 64 scalar b16 stores. XCD-swizzled block ids.
// c_mode: 0 = per-flag row-major, 1 = bf16 row-major, 2 = vt[bt][h][dd][n].
// ---------------------------------------------------------------------------
__global__ __launch_bounds__(256)
void gemm_k512(const void* __restrict__ A, const short* __restrict__ Bt,
               const void* __restrict__ bias, void* __restrict__ C,
               const int* __restrict__ dflag, int a_mode, int c_mode, int relu)
{
  __shared__ alignas(16) short As[128*32];
  __shared__ alignas(16) short Bs[128*32];
  const int isbf = *dflag;
  const int a_bf = a_mode ? 1 : isbf;
  const int tid  = threadIdx.x;
  const int wave = tid >> 6, lane = tid & 63;
  const int l15 = lane & 15, lq = lane >> 4;
  // grid = 1536 (%8==0) -> bijective XCD swizzle; consecutive work ids
  // (one A-panel x 4 n-tiles) stay on one XCD's L2.
  const int bxs = (int)((blockIdx.x & 7) * (gridDim.x >> 3) + (blockIdx.x >> 3));
  const int m0 = (bxs >> 2) * 128;
  const int n0 = (bxs & 3) * 128;
  const int wy = wave >> 1, wx = wave & 1;

  floatx4 acc[4][4] = {};

  const short* A16 = (const short*)A + (size_t)m0 * 512;
  const float* A32 = (const float*)A + (size_t)m0 * 512;
  const short* Bb  = Bt + (size_t)n0 * 512;
  const int c0 = wave*128 + lane;

  for (int kt = 0; kt < 16; ++kt) {
    const int k0 = kt * 32;
    __syncthreads();
    if (a_bf) {
#pragma unroll
      for (int i = 0; i < 2; ++i) {
        const int c = c0 + i*64;
        gll16(&A16[(size_t)(c>>2)*512 + k0 + (c&3)*8], (void*)&As[(wave*128 + i*64)*8]);
      }
    } else {
#pragma unroll
      for (int i = 0; i < 2; ++i) {
        const int c = tid + i*256;
        const size_t gi = (size_t)(c>>2)*512 + k0 + (c&3)*8;
        const f32x4 f0 = *(const f32x4*)&A32[gi];
        const f32x4 f1 = *(const f32x4*)&A32[gi+4];
        short8 o;
#pragma unroll
        for (int j=0;j<4;++j) { o[j] = f2b(f0[j]); o[4+j] = f2b(f1[j]); }
        *(short8*)&As[c*8] = o;
      }
    }
#pragma unroll
    for (int i = 0; i < 2; ++i) {
      const int c = c0 + i*64;
      gll16(&Bb[(size_t)(c>>2)*512 + k0 + (c&3)*8], (void*)&Bs[(wave*128 + i*64)*8]);
    }
    __syncthreads();

    short8 af[4], bfm[4];
#pragma unroll
    for (int mt=0; mt<4; ++mt)
      af[mt] = *(const short8*)&As[(wy*64 + mt*16 + l15)*32 + lq*8];
#pragma unroll
    for (int nt=0; nt<4; ++nt)
      bfm[nt] = *(const short8*)&Bs[(wx*64 + nt*16 + l15)*32 + lq*8];
    // swapped: acc[mt][nt][r] = C[m0+wy*64+mt*16+l15][n0+wx*64+nt*16+lq*4+r]
#pragma unroll
    for (int mt=0; mt<4; ++mt)
#pragma unroll
      for (int nt=0; nt<4; ++nt)
        acc[mt][nt] = MFMA16(bfm[nt], af[mt], acc[mt][nt]);
  }

#pragma unroll
  for (int nt=0; nt<4; ++nt) {
    const int cb = n0 + wx*64 + nt*16 + lq*4;
    float b4[4];
#pragma unroll
    for (int r=0; r<4; ++r) b4[r] = loadf(bias, cb + r, isbf);
#pragma unroll
    for (int mt=0; mt<4; ++mt) {
      const int row = m0 + wy*64 + mt*16 + l15;
      float v[4];
#pragma unroll
      for (int r=0; r<4; ++r) {
        v[r] = acc[mt][nt][r] + b4[r];
        if (relu) v[r] = fmaxf(v[r], 0.0f);
      }
      if (c_mode == 1) {
        s4v o;
#pragma unroll
        for (int r=0; r<4; ++r) o[r] = f2b(v[r]);
        *(s4v*)&((short*)C)[(size_t)row*512 + cb] = o;
      } else if (c_mode == 2) {
        const int bt = row >> 9, n = row & 511;
#pragma unroll
        for (int r=0; r<4; ++r) {
          const int col = cb + r;
          const int hI = col >> 6, dd = col & 63;
          ((short*)C)[(((size_t)bt*8 + hI)*64 + dd)*512 + n] = f2b(v[r]);
        }
      } else {
        if (isbf) {
          s4v o;
#pragma unroll
          for (int r=0; r<4; ++r) o[r] = f2b(v[r]);
          *(s4v*)&((short*)C)[(size_t)row*512 + cb] = o;
        } else {
          f32x4 o;
#pragma unroll
          for (int r=0; r<4; ++r) o[r] = v[r];
          *(f32x4*)&((float*)C)[(size_t)row*512 + cb] = o;
        }
      }
    }
  }
}

// ---------------------------------------------------------------------------
// Flash attention over nodes (no max-tracking: post-ReLU scores are small).
// SWAPPED QK^T (mfma(K,Q) -> S^T): each lane's 4 C-values are 4 consecutive
// kv for one q-row => P write is one packed ds_write_b64 per (qt,mt) instead
// of 8 scalar b16 writes, and the softmax row-sum is lane-local (4 partials,
// 2 shuffles each at the end). PV also swapped (mfma(V,P) -> O^T): lane holds
// 4 consecutive dd for one q-row => packed 8B O stores, denominator already
// lane-local. __launch_bounds__(256,4) caps VGPR at 128 -> 4 blocks/CU.
// ---------------------------------------------------------------------------
__global__ __launch_bounds__(256, 4)
void attn_k(const short* Q, const short* __restrict__ Kb,
            const short* __restrict__ Vt, short* O)
{
  __shared__ alignas(16) short KT[64*72];     // [kv][e], padded
  __shared__ alignas(16) short VTs[64*72];    // [dd][kv], padded
  __shared__ alignas(16) short PBh[4*64*40];  // per-wave P half [q][kv32], padded

  const int tid  = threadIdx.x;
  const int wave = tid >> 6, lane = tid & 63;
  const int l15 = lane & 15, lq = lane >> 4;
  // bijective XCD swizzle (1536 % 8 == 0): the rb=0/1 pair sharing K/V lands
  // on one XCD's L2.
  const int bx = (int)((blockIdx.x & 7) * (gridDim.x >> 3) + (blockIdx.x >> 3));
  const int bt = bx >> 4;
  const int h  = (bx >> 1) & 7;
  const int rb = bx & 1;

  const size_t qbase = ((size_t)bt*512 + rb*256) * 512 + h*64;

  // q fragments direct global->register (used as MFMA B operand)
  short8 qf[4][2];
#pragma unroll
  for (int qt=0; qt<4; ++qt)
#pragma unroll
    for (int kd=0; kd<2; ++kd)
      qf[qt][kd] = *(const short8*)&Q[qbase + (size_t)(wave*64 + qt*16 + l15)*512 + kd*32 + lq*8];

  floatx4 oacc[4][4] = {};   // oacc[qt][nt][r] = O[qt*16+l15][nt*16+lq*4+r]
  float lsum[4] = {};        // partial denom for q = qt*16+l15 over lane's kv subset

  const float cs = 0.18033688011112042f;  // log2(e)/sqrt(64)
  const size_t kbase = (size_t)bt*512*512 + h*64;
  const size_t vbase = ((size_t)bt*8 + h) * (size_t)64*512;
  short* PW = &PBh[wave*64*40];

  for (int it = 0; it < 8; ++it) {
    const int kv0 = it*64;
    __syncthreads();
#pragma unroll
    for (int i = 0; i < 2; ++i) {
      const int c = tid + i*256;   // KT: kv=c>>3, grp=c&7; VTs: dd=c>>3
      *(short8*)&KT[(c>>3)*72 + (c&7)*8] =
          *(const short8*)&Kb[kbase + (size_t)(kv0 + (c>>3))*512 + (c&7)*8];
      *(short8*)&VTs[(c>>3)*72 + (c&7)*8] =
          *(const short8*)&Vt[vbase + (size_t)(c>>3)*512 + kv0 + (c&7)*8];
    }
    __syncthreads();

#pragma unroll
    for (int half = 0; half < 2; ++half) {
      // S^T per kv-16-subtile: st[qt][r] = S[kv=half*32+mt*16+lq*4+r][q=qt*16+l15]
#pragma unroll
      for (int mt = 0; mt < 2; ++mt) {
        floatx4 st[4] = {};
#pragma unroll
        for (int kd = 0; kd < 2; ++kd) {
          const short8 kf = *(const short8*)&KT[(half*32 + mt*16 + l15)*72 + kd*32 + lq*8];
          __builtin_amdgcn_s_setprio(1);
#pragma unroll
          for (int qt=0; qt<4; ++qt)
            st[qt] = MFMA16(kf, qf[qt][kd], st[qt]);
          __builtin_amdgcn_s_setprio(0);
        }
        // exp, lane-local row-sum partials, packed P write (4 consecutive kv)
#pragma unroll
        for (int qt=0; qt<4; ++qt) {
          const float p0 = exp2f(st[qt][0] * cs);
          const float p1 = exp2f(st[qt][1] * cs);
          const float p2 = exp2f(st[qt][2] * cs);
          const float p3 = exp2f(st[qt][3] * cs);
          lsum[qt] += (p0 + p1) + (p2 + p3);
          s4v pk;
          pk[0] = f2b(p0); pk[1] = f2b(p1); pk[2] = f2b(p2); pk[3] = f2b(p3);
          *(s4v*)&PW[(qt*16 + l15)*40 + mt*16 + lq*4] = pk;
        }
      }
      // O^T += V_half x P_half (swapped): A=V rows (dd), B=P rows (q)
      short8 bfr[4];
#pragma unroll
      for (int nt=0; nt<4; ++nt)
        bfr[nt] = *(const short8*)&VTs[(nt*16 + l15)*72 + half*32 + lq*8];
#pragma unroll
      for (int qt=0; qt<4; ++qt) {
        const short8 af = *(const short8*)&PW[(qt*16 + l15)*40 + lq*8];
        __builtin_amdgcn_s_setprio(1);
#pragma unroll
        for (int nt=0; nt<4; ++nt)
          oacc[qt][nt] = MFMA16(bfr[nt], af, oacc[qt][nt]);
        __builtin_amdgcn_s_setprio(0);
      }
    }
  }

  // denominators: sum over the 4 lq groups sharing l15
#pragma unroll
  for (int qt=0; qt<4; ++qt) {
    float s = lsum[qt];
    s += __shfl_xor(s, 16, 64);
    s += __shfl_xor(s, 32, 64);
    lsum[qt] = 1.0f / s;
  }
  const size_t obase = ((size_t)bt*512 + rb*256 + wave*64) * 512 + h*64;
#pragma unroll
  for (int qt=0; qt<4; ++qt) {
    const int q = qt*16 + l15;
#pragma unroll
    for (int nt=0; nt<4; ++nt) {
      s4v o;
#pragma unroll
      for (int r=0; r<4; ++r) o[r] = f2b(oacc[qt][nt][r] * lsum[qt]);
      *(s4v*)&O[obase + (size_t)q*512 + nt*16 + lq*4] = o;
    }
  }
}

// ---------------------------------------------------------------------------
extern "C" void kernel_launch(void* const* d_in, const int* in_sizes, int n_in,
                              void* d_out, int out_size, void* d_ws, size_t ws_size,
                              hipStream_t stream)
{
  const void* X  = d_in[0];
  const void* Wq = d_in[2];
  const void* bq = d_in[3];
  const void* Wk = d_in[4];
  const void* bk = d_in[5];
  const void* Wv = d_in[6];
  const void* bv = d_in[7];
  const void* W1 = d_in[8];
  const void* b1 = d_in[9];
  const void* W2 = d_in[10];
  const void* b2 = d_in[11];

  char* ws = (char*)d_ws;
  int* dflag = (int*)ws;
  const size_t SZe = (size_t)49152 * 512;
  short* kbuf = (short*)(ws + 256);
  short* vt   = kbuf + SZe;
  short* wt   = vt + SZe;
  short* xb   = wt + (size_t)5 * 262144;
  const size_t need = 256 + 2 * (3*SZe + (size_t)5*262144);
  const int use_xb = (ws_size >= need) ? 1 : 0;

  short* q    = (short*)d_out;
  short* ao   = q;
  short* hh   = kbuf;

  sniff_dtype<<<1, 64, 0, stream>>>((const uint32_t*)X, dflag);
  transpose_w<<<320, 256, 0, stream>>>(Wq, Wk, Wv, W1, W2, wt, dflag);
  if (use_xb) {
    cvt_x<<<2048, 256, 0, stream>>>(X, xb, dflag);
    gemm_k512<<<1536, 256, 0, stream>>>(xb, wt,           bq, q,     dflag, 1, 1, 1);
    gemm_k512<<<1536, 256, 0, stream>>>(xb, wt + 262144,  bk, kbuf,  dflag, 1, 1, 1);
    gemm_k512<<<1536, 256, 0, stream>>>(xb, wt + 524288,  bv, vt,    dflag, 1, 2, 1);
  } else {
    gemm_k512<<<1536, 256, 0, stream>>>(X,  wt,           bq, q,     dflag, 0, 1, 1);
    gemm_k512<<<1536, 256, 0, stream>>>(X,  wt + 262144,  bk, kbuf,  dflag, 0, 1, 1);
    gemm_k512<<<1536, 256, 0, stream>>>(X,  wt + 524288,  bv, vt,    dflag, 0, 2, 1);
  }
  attn_k<<<1536, 256, 0, stream>>>(q, kbuf, vt, ao);
  gemm_k512<<<1536, 256, 0, stream>>>(ao, wt + 786432,  b1, hh,    dflag, 1, 1, 1);
  gemm_k512<<<1536, 256, 0, stream>>>(hh, wt + 1048576, b2, d_out, dflag, 1, 0, 0);
}

// Round 2
// 562.761 us; speedup vs baseline: 1.6611x; 1.6611x over previous
//
#include <hip/hip_runtime.h>
#include <hip/hip_bf16.h>
#include <stdint.h>

typedef short s4v    __attribute__((ext_vector_type(4)));
typedef short short8 __attribute__((ext_vector_type(8)));
typedef float f32x4  __attribute__((ext_vector_type(4)));
typedef float floatx4 __attribute__((ext_vector_type(4)));

#define MFMA16(a,b,c) __builtin_amdgcn_mfma_f32_16x16x32_bf16((a),(b),(c),0,0,0)

typedef __attribute__((address_space(3))) void* lds_ptr_t;
typedef __attribute__((address_space(1))) void* gbl_ptr_t;

// async global->LDS, 16B/lane; LDS dest = wave-uniform base + lane*16.
__device__ __forceinline__ void gll16(const void* g, void* l) {
  __builtin_amdgcn_global_load_lds((gbl_ptr_t)g, (lds_ptr_t)l, 16, 0, 0);
}

__device__ __forceinline__ short f2b(float f) {
  return __builtin_bit_cast(short, __float2bfloat16(f));
}
__device__ __forceinline__ float b2f(short s) {
  return __bfloat162float(__builtin_bit_cast(__hip_bfloat16, s));
}
__device__ __forceinline__ float loadf(const void* p, size_t i, int isbf) {
  return isbf ? b2f(((const short*)p)[i]) : ((const float*)p)[i];
}

// ---------------------------------------------------------------------------
// Dtype sniffer (1 = bf16, 0 = fp32), written to device flag.
// ---------------------------------------------------------------------------
__global__ void sniff_dtype(const uint32_t* __restrict__ X, int* __restrict__ flag)
{
  const int t = threadIdx.x;
  const uint32_t w = X[t];
  const uint32_t b = (w >> 8) & 0x7fu;
  const int hit = (b >= 0x38u && b <= 0x41u) ? 1 : 0;
  const unsigned long long m = __ballot(hit);
  if (t == 0) flag[0] = (__popcll(m) > 32) ? 1 : 0;
}

// ---------------------------------------------------------------------------
// Transpose 5 512x512 weights into bf16 Wt[n][k].
// ---------------------------------------------------------------------------
__global__ __launch_bounds__(256)
void transpose_w(const void* __restrict__ Wq, const void* __restrict__ Wk,
                 const void* __restrict__ Wv, const void* __restrict__ W1,
                 const void* __restrict__ W2, short* __restrict__ Out,
                 const int* __restrict__ dflag)
{
  __shared__ short tile[64][65];
  const int isbf = *dflag;
  const int b = blockIdx.x;          // 5 * 64
  const int w = b >> 6;
  const int t = b & 63;
  const int ty = t >> 3, tx = t & 7;
  const void* W = (w==0)?Wq:(w==1)?Wk:(w==2)?Wv:(w==3)?W1:W2;
  short* Og = Out + (size_t)w * 262144;
  const int tid = threadIdx.x;
#pragma unroll
  for (int i=0;i<16;++i) {
    const int idx = tid + i*256;
    const int rr = idx>>6, cc = idx&63;
    tile[rr][cc] = f2b(loadf(W, (size_t)(ty*64+rr)*512 + tx*64 + cc, isbf));
  }
  __syncthreads();
#pragma unroll
  for (int i=0;i<16;++i) {
    const int idx = tid + i*256;
    const int co = idx>>6, ko = idx&63;
    Og[(size_t)(tx*64+co)*512 + ty*64 + ko] = tile[ko][co];
  }
}

// ---------------------------------------------------------------------------
// One-shot X convert: fp32 (or bf16 passthrough) -> bf16 row-major, so the
// QKV GEMMs can use the global_load_lds width-16 staging path.
// ---------------------------------------------------------------------------
__global__ __launch_bounds__(256)
void cvt_x(const void* __restrict__ X, short* __restrict__ Xb,
           const int* __restrict__ dflag)
{
  const int isbf = *dflag;
  const size_t n8 = (size_t)49152 * 512 / 8;
  const size_t stride = (size_t)gridDim.x * 256;
  for (size_t i = (size_t)blockIdx.x * 256 + threadIdx.x; i < n8; i += stride) {
    if (isbf) {
      *(short8*)&Xb[i*8] = *(const short8*)&((const short*)X)[i*8];
    } else {
      const f32x4 f0 = *(const f32x4*)&((const float*)X)[i*8];
      const f32x4 f1 = *(const f32x4*)&((const float*)X)[i*8+4];
      short8 o;
#pragma unroll
      for (int j=0;j<4;++j) { o[j] = f2b(f0[j]); o[4+j] = f2b(f1[j]); }
      *(short8*)&Xb[i*8] = o;
    }
  }
}

// ---------------------------------------------------------------------------
// GEMM: C[M,512] = act(A[M,512] @ Bt^T + bias), M=49152. 128x128 tile, BK=32,
// 4 waves, m97 structure. MFMA operands SWAPPED (mfma(B,A)) so each lane's
// 4 accumulator values are 4 CONSECUTIVE output columns -> packed 8B/16B
// epilogue stores instead of 64 scalar b16 stores. XCD-swizzled block ids.
// c_mode: 0 = per-flag row-major, 1 = bf16 row-major, 2 = vt[bt][h][dd][n].
// ---------------------------------------------------------------------------
__global__ __launch_bounds__(256)
void gemm_k512(const void* __restrict__ A, const short* __restrict__ Bt,
               const void* __restrict__ bias, void* __restrict__ C,
               const int* __restrict__ dflag, int a_mode, int c_mode, int relu)
{
  __shared__ alignas(16) short As[128*32];
  __shared__ alignas(16) short Bs[128*32];
  const int isbf = *dflag;
  const int a_bf = a_mode ? 1 : isbf;
  const int tid  = threadIdx.x;
  const int wave = tid >> 6, lane = tid & 63;
  const int l15 = lane & 15, lq = lane >> 4;
  // grid = 1536 (%8==0) -> bijective XCD swizzle; consecutive work ids
  // (one A-panel x 4 n-tiles) stay on one XCD's L2.
  const int bxs = (int)((blockIdx.x & 7) * (gridDim.x >> 3) + (blockIdx.x >> 3));
  const int m0 = (bxs >> 2) * 128;
  const int n0 = (bxs & 3) * 128;
  const int wy = wave >> 1, wx = wave & 1;

  floatx4 acc[4][4] = {};

  const short* A16 = (const short*)A + (size_t)m0 * 512;
  const float* A32 = (const float*)A + (size_t)m0 * 512;
  const short* Bb  = Bt + (size_t)n0 * 512;
  const int c0 = wave*128 + lane;

  for (int kt = 0; kt < 16; ++kt) {
    const int k0 = kt * 32;
    __syncthreads();
    if (a_bf) {
#pragma unroll
      for (int i = 0; i < 2; ++i) {
        const int c = c0 + i*64;
        gll16(&A16[(size_t)(c>>2)*512 + k0 + (c&3)*8], (void*)&As[(wave*128 + i*64)*8]);
      }
    } else {
#pragma unroll
      for (int i = 0; i < 2; ++i) {
        const int c = tid + i*256;
        const size_t gi = (size_t)(c>>2)*512 + k0 + (c&3)*8;
        const f32x4 f0 = *(const f32x4*)&A32[gi];
        const f32x4 f1 = *(const f32x4*)&A32[gi+4];
        short8 o;
#pragma unroll
        for (int j=0;j<4;++j) { o[j] = f2b(f0[j]); o[4+j] = f2b(f1[j]); }
        *(short8*)&As[c*8] = o;
      }
    }
#pragma unroll
    for (int i = 0; i < 2; ++i) {
      const int c = c0 + i*64;
      gll16(&Bb[(size_t)(c>>2)*512 + k0 + (c&3)*8], (void*)&Bs[(wave*128 + i*64)*8]);
    }
    __syncthreads();

    short8 af[4], bfm[4];
#pragma unroll
    for (int mt=0; mt<4; ++mt)
      af[mt] = *(const short8*)&As[(wy*64 + mt*16 + l15)*32 + lq*8];
#pragma unroll
    for (int nt=0; nt<4; ++nt)
      bfm[nt] = *(const short8*)&Bs[(wx*64 + nt*16 + l15)*32 + lq*8];
    // swapped: acc[mt][nt][r] = C[m0+wy*64+mt*16+l15][n0+wx*64+nt*16+lq*4+r]
#pragma unroll
    for (int mt=0; mt<4; ++mt)
#pragma unroll
      for (int nt=0; nt<4; ++nt)
        acc[mt][nt] = MFMA16(bfm[nt], af[mt], acc[mt][nt]);
  }

#pragma unroll
  for (int nt=0; nt<4; ++nt) {
    const int cb = n0 + wx*64 + nt*16 + lq*4;
    float b4[4];
#pragma unroll
    for (int r=0; r<4; ++r) b4[r] = loadf(bias, cb + r, isbf);
#pragma unroll
    for (int mt=0; mt<4; ++mt) {
      const int row = m0 + wy*64 + mt*16 + l15;
      float v[4];
#pragma unroll
      for (int r=0; r<4; ++r) {
        v[r] = acc[mt][nt][r] + b4[r];
        if (relu) v[r] = fmaxf(v[r], 0.0f);
      }
      if (c_mode == 1) {
        s4v o;
#pragma unroll
        for (int r=0; r<4; ++r) o[r] = f2b(v[r]);
        *(s4v*)&((short*)C)[(size_t)row*512 + cb] = o;
      } else if (c_mode == 2) {
        const int bt = row >> 9, n = row & 511;
#pragma unroll
        for (int r=0; r<4; ++r) {
          const int col = cb + r;
          const int hI = col >> 6, dd = col & 63;
          ((short*)C)[(((size_t)bt*8 + hI)*64 + dd)*512 + n] = f2b(v[r]);
        }
      } else {
        if (isbf) {
          s4v o;
#pragma unroll
          for (int r=0; r<4; ++r) o[r] = f2b(v[r]);
          *(s4v*)&((short*)C)[(size_t)row*512 + cb] = o;
        } else {
          f32x4 o;
#pragma unroll
          for (int r=0; r<4; ++r) o[r] = v[r];
          *(f32x4*)&((float*)C)[(size_t)row*512 + cb] = o;
        }
      }
    }
  }
}

// ---------------------------------------------------------------------------
// Flash attention over nodes (no max-tracking: post-ReLU scores are small).
// SWAPPED QK^T (mfma(K,Q) -> S^T): each lane's 4 C-values are 4 consecutive
// kv for one q-row => P write is one packed ds_write_b64 per (qt,mt) instead
// of 8 scalar b16 writes, and the softmax row-sum is lane-local. PV also
// swapped (mfma(V,P) -> O^T): lane holds 4 consecutive dd for one q-row =>
// packed 8B O stores, denominator already lane-local.
// NOTE: no min-waves floor in launch_bounds — (256,4) forced VGPR=64 and the
// accumulators spilled to scratch (WRITE_SIZE 49MB -> 1GB, 2.2x slower).
// ---------------------------------------------------------------------------
__global__ __launch_bounds__(256)
void attn_k(const short* Q, const short* __restrict__ Kb,
            const short* __restrict__ Vt, short* O)
{
  __shared__ alignas(16) short KT[64*72];     // [kv][e], padded
  __shared__ alignas(16) short VTs[64*72];    // [dd][kv], padded
  __shared__ alignas(16) short PBh[4*64*40];  // per-wave P half [q][kv32], padded

  const int tid  = threadIdx.x;
  const int wave = tid >> 6, lane = tid & 63;
  const int l15 = lane & 15, lq = lane >> 4;
  // bijective XCD swizzle (1536 % 8 == 0): the rb=0/1 pair sharing K/V lands
  // on one XCD's L2.
  const int bx = (int)((blockIdx.x & 7) * (gridDim.x >> 3) + (blockIdx.x >> 3));
  const int bt = bx >> 4;
  const int h  = (bx >> 1) & 7;
  const int rb = bx & 1;

  const size_t qbase = ((size_t)bt*512 + rb*256) * 512 + h*64;

  // q fragments direct global->register (used as MFMA B operand)
  short8 qf[4][2];
#pragma unroll
  for (int qt=0; qt<4; ++qt)
#pragma unroll
    for (int kd=0; kd<2; ++kd)
      qf[qt][kd] = *(const short8*)&Q[qbase + (size_t)(wave*64 + qt*16 + l15)*512 + kd*32 + lq*8];

  floatx4 oacc[4][4] = {};   // oacc[qt][nt][r] = O[qt*16+l15][nt*16+lq*4+r]
  float lsum[4] = {};        // partial denom for q = qt*16+l15 over lane's kv subset

  const float cs = 0.18033688011112042f;  // log2(e)/sqrt(64)
  const size_t kbase = (size_t)bt*512*512 + h*64;
  const size_t vbase = ((size_t)bt*8 + h) * (size_t)64*512;
  short* PW = &PBh[wave*64*40];

  for (int it = 0; it < 8; ++it) {
    const int kv0 = it*64;
    __syncthreads();
#pragma unroll
    for (int i = 0; i < 2; ++i) {
      const int c = tid + i*256;   // KT: kv=c>>3, grp=c&7; VTs: dd=c>>3
      *(short8*)&KT[(c>>3)*72 + (c&7)*8] =
          *(const short8*)&Kb[kbase + (size_t)(kv0 + (c>>3))*512 + (c&7)*8];
      *(short8*)&VTs[(c>>3)*72 + (c&7)*8] =
          *(const short8*)&Vt[vbase + (size_t)(c>>3)*512 + kv0 + (c&7)*8];
    }
    __syncthreads();

#pragma unroll
    for (int half = 0; half < 2; ++half) {
      // S^T per kv-16-subtile: st[qt][r] = S[kv=half*32+mt*16+lq*4+r][q=qt*16+l15]
#pragma unroll
      for (int mt = 0; mt < 2; ++mt) {
        floatx4 st[4] = {};
#pragma unroll
        for (int kd = 0; kd < 2; ++kd) {
          const short8 kf = *(const short8*)&KT[(half*32 + mt*16 + l15)*72 + kd*32 + lq*8];
          __builtin_amdgcn_s_setprio(1);
#pragma unroll
          for (int qt=0; qt<4; ++qt)
            st[qt] = MFMA16(kf, qf[qt][kd], st[qt]);
          __builtin_amdgcn_s_setprio(0);
        }
        // exp, lane-local row-sum partials, packed P write (4 consecutive kv)
#pragma unroll
        for (int qt=0; qt<4; ++qt) {
          const float p0 = exp2f(st[qt][0] * cs);
          const float p1 = exp2f(st[qt][1] * cs);
          const float p2 = exp2f(st[qt][2] * cs);
          const float p3 = exp2f(st[qt][3] * cs);
          lsum[qt] += (p0 + p1) + (p2 + p3);
          s4v pk;
          pk[0] = f2b(p0); pk[1] = f2b(p1); pk[2] = f2b(p2); pk[3] = f2b(p3);
          *(s4v*)&PW[(qt*16 + l15)*40 + mt*16 + lq*4] = pk;
        }
      }
      // O^T += V_half x P_half (swapped): A=V rows (dd), B=P rows (q)
      short8 bfr[4];
#pragma unroll
      for (int nt=0; nt<4; ++nt)
        bfr[nt] = *(const short8*)&VTs[(nt*16 + l15)*72 + half*32 + lq*8];
#pragma unroll
      for (int qt=0; qt<4; ++qt) {
        const short8 af = *(const short8*)&PW[(qt*16 + l15)*40 + lq*8];
        __builtin_amdgcn_s_setprio(1);
#pragma unroll
        for (int nt=0; nt<4; ++nt)
          oacc[qt][nt] = MFMA16(bfr[nt], af, oacc[qt][nt]);
        __builtin_amdgcn_s_setprio(0);
      }
    }
  }

  // denominators: sum over the 4 lq groups sharing l15
#pragma unroll
  for (int qt=0; qt<4; ++qt) {
    float s = lsum[qt];
    s += __shfl_xor(s, 16, 64);
    s += __shfl_xor(s, 32, 64);
    lsum[qt] = 1.0f / s;
  }
  const size_t obase = ((size_t)bt*512 + rb*256 + wave*64) * 512 + h*64;
#pragma unroll
  for (int qt=0; qt<4; ++qt) {
    const int q = qt*16 + l15;
#pragma unroll
    for (int nt=0; nt<4; ++nt) {
      s4v o;
#pragma unroll
      for (int r=0; r<4; ++r) o[r] = f2b(oacc[qt][nt][r] * lsum[qt]);
      *(s4v*)&O[obase + (size_t)q*512 + nt*16 + lq*4] = o;
    }
  }
}

// ---------------------------------------------------------------------------
extern "C" void kernel_launch(void* const* d_in, const int* in_sizes, int n_in,
                              void* d_out, int out_size, void* d_ws, size_t ws_size,
                              hipStream_t stream)
{
  const void* X  = d_in[0];
  const void* Wq = d_in[2];
  const void* bq = d_in[3];
  const void* Wk = d_in[4];
  const void* bk = d_in[5];
  const void* Wv = d_in[6];
  const void* bv = d_in[7];
  const void* W1 = d_in[8];
  const void* b1 = d_in[9];
  const void* W2 = d_in[10];
  const void* b2 = d_in[11];

  char* ws = (char*)d_ws;
  int* dflag = (int*)ws;
  const size_t SZe = (size_t)49152 * 512;
  short* kbuf = (short*)(ws + 256);
  short* vt   = kbuf + SZe;
  short* wt   = vt + SZe;
  short* xb   = wt + (size_t)5 * 262144;
  const size_t need = 256 + 2 * (3*SZe + (size_t)5*262144);
  const int use_xb = (ws_size >= need) ? 1 : 0;

  short* q    = (short*)d_out;
  short* ao   = q;
  short* hh   = kbuf;

  sniff_dtype<<<1, 64, 0, stream>>>((const uint32_t*)X, dflag);
  transpose_w<<<320, 256, 0, stream>>>(Wq, Wk, Wv, W1, W2, wt, dflag);
  if (use_xb) {
    cvt_x<<<2048, 256, 0, stream>>>(X, xb, dflag);
    gemm_k512<<<1536, 256, 0, stream>>>(xb, wt,           bq, q,     dflag, 1, 1, 1);
    gemm_k512<<<1536, 256, 0, stream>>>(xb, wt + 262144,  bk, kbuf,  dflag, 1, 1, 1);
    gemm_k512<<<1536, 256, 0, stream>>>(xb, wt + 524288,  bv, vt,    dflag, 1, 2, 1);
  } else {
    gemm_k512<<<1536, 256, 0, stream>>>(X,  wt,           bq, q,     dflag, 0, 1, 1);
    gemm_k512<<<1536, 256, 0, stream>>>(X,  wt + 262144,  bk, kbuf,  dflag, 0, 1, 1);
    gemm_k512<<<1536, 256, 0, stream>>>(X,  wt + 524288,  bv, vt,    dflag, 0, 2, 1);
  }
  attn_k<<<1536, 256, 0, stream>>>(q, kbuf, vt, ao);
  gemm_k512<<<1536, 256, 0, stream>>>(ao, wt + 786432,  b1, hh,    dflag, 1, 1, 1);
  gemm_k512<<<1536, 256, 0, stream>>>(hh, wt + 1048576, b2, d_out, dflag, 1, 0, 0);
}